// Round 6
// baseline (342.860 us; speedup 1.0000x reference)
//
#include <hip/hip_runtime.h>
#include <cstdint>
#include <cstddef>

#define BATCH 8192
#define KC 8
#define NC 1024
#define DC 256
// Single-pass f16 GEMM: measured flag-rate at TAU=0.15 was 1.5% (cnt~960,
// matching the Exp(11.7) top-2-gap model; noise sigma ~0.009 on the gap).
// TAU = 0.10 ~ 11 sigma: cnt ~640, miss probability ~1e-9 per run.
#define TAU 0.10f

typedef __attribute__((ext_vector_type(8))) _Float16 half8;
typedef __attribute__((ext_vector_type(4))) _Float16 half4;
typedef __attribute__((ext_vector_type(4))) float floatx4;

__device__ __forceinline__ void async_load16(const void* g, void* l) {
    __builtin_amdgcn_global_load_lds((const __attribute__((address_space(1))) uint32_t*)g,
                                     (__attribute__((address_space(3))) uint32_t*)l, 16, 0, 0);
}

// XOR-swizzled 16KB LDS sub-tile (128 rows x 64 halfs): row r, 16B chunk c at slot c^(r&7)
__device__ __forceinline__ int lidx(int r, int c) {
    return (r >> 3) * 1024 + (r & 7) * 128 + ((c ^ (r & 7)) * 16);
}
__device__ __forceinline__ half8 ldsr(const char* base, int r, int c) {
    return *(const half8*)(base + lidx(r, c));
}

// ---------------------------------------------------------------------------
// P: entries -> Eh f16 [row][256]; eef = fp32(|e|^2 via fp64)
// ---------------------------------------------------------------------------
__global__ __launch_bounds__(256) void prep_e_kernel(const float* __restrict__ entries,
                                                     _Float16* __restrict__ Ecat,
                                                     float* __restrict__ eef) {
    int wave = threadIdx.x >> 6, lane = threadIdx.x & 63;
    int row = blockIdx.x * 4 + wave;            // [0, 8192) = k*NC + n
    float4 v = ((const float4*)(entries + (size_t)row * DC))[lane];
    half4 h;
    h.x = (_Float16)v.x; h.y = (_Float16)v.y; h.z = (_Float16)v.z; h.w = (_Float16)v.w;
    *(half4*)(Ecat + (size_t)row * 256 + lane * 4) = h;
    double s = (double)v.x * v.x + (double)v.y * v.y + (double)v.z * v.z + (double)v.w * v.w;
    #pragma unroll
    for (int off = 32; off > 0; off >>= 1) s += __shfl_down(s, off, 64);
    if (lane == 0) eef[row] = (float)s;
}

// ---------------------------------------------------------------------------
// GEMM: grid 512 (k = blk&7 -> XCD-pinned, bt = blk>>3). 4 waves x 32 rows.
// SINGLE-PASS f16 (xh*eh only): 1/3 the MFMA work of the split-f16 3-pass;
// accuracy recovered by TAU flagging + fp64 refine (~1% of rows).
// A full-K in registers (64 VGPR). B streamed via global_load_lds into a
// 2-ring of 32KB stage buffers (128-dim slices = 2 swizzled 16KB subtiles).
// ---------------------------------------------------------------------------
__global__ __launch_bounds__(256, 2) void vq_gemm(const float* __restrict__ x,
                                                  const float* __restrict__ entries,
                                                  const _Float16* __restrict__ Ecat,
                                                  const float* __restrict__ eef,
                                                  float* __restrict__ out_idx,
                                                  float* __restrict__ out_q,
                                                  double* __restrict__ partial,
                                                  int* __restrict__ flag_list,
                                                  int* __restrict__ flag_cnt) {
    __shared__ alignas(16) char Bst[2][32768];   // buf = 2 x 16KB subtiles (64 dims each)
    __shared__ float eef_lds[NC];
    __shared__ float tv1[128];
    __shared__ float tv2[128];
    __shared__ int   ti1[128];
    __shared__ int   idx_lds[128];
    __shared__ double red[256];

    const int t = threadIdx.x;
    const int k  = blockIdx.x & 7;
    const int b0 = (blockIdx.x >> 3) * 128;
    const int w = t >> 6, lane = t & 63;
    const int quad = lane >> 4, col = lane & 15;
    const int rl = lane >> 3;
    const int cs = (lane & 7) ^ rl;

    { float4 v = ((const float4*)(eef + (size_t)k * NC))[t]; *(float4*)(eef_lds + t * 4) = v; }
    if (t < 128) { tv1[t] = 1e30f; tv2[t] = 1e30f; ti1[t] = 0; }

    // ---- A fragments: full K=256 in registers, plain f16 ----
    half8 Ah[2][8];
    #pragma unroll
    for (int mi = 0; mi < 2; ++mi) {
        const float* xrow = x + ((size_t)(b0 + w * 32 + mi * 16 + col) * KC + k) * DC + quad * 8;
        #pragma unroll
        for (int ks = 0; ks < 8; ++ks) {
            float4 u0 = *(const float4*)(xrow + ks * 32);
            float4 u1 = *(const float4*)(xrow + ks * 32 + 4);
            float f[8] = {u0.x, u0.y, u0.z, u0.w, u1.x, u1.y, u1.z, u1.w};
            half8 h;
            #pragma unroll
            for (int j = 0; j < 8; ++j) h[j] = (_Float16)f[j];
            Ah[mi][ks] = h;
        }
    }

    const char* EcatK = (const char*)(Ecat + (size_t)k * NC * 256);   // 512B per col

    #define ISSUE_B(nt_, h_)                                                             \
        {                                                                                \
            char* bb_ = Bst[h_];                                                         \
            _Pragma("unroll")                                                            \
            for (int j = 0; j < 8; ++j) {                                                \
                int li_ = w * 8 + j; int sub_ = li_ >> 4, grp_ = li_ & 15;               \
                const char* src_ = EcatK + (size_t)((nt_) * 128 + grp_ * 8 + rl) * 512   \
                                 + ((h_) * 128 + sub_ * 64) * 2 + cs * 16;               \
                async_load16(src_, bb_ + sub_ * 16384 + grp_ * 1024 + lane * 16);        \
            }                                                                            \
        }

    #define STAGE(h_, DOISS_, nti_)                                                      \
        {                                                                                \
            asm volatile("s_waitcnt vmcnt(0)" ::: "memory");                             \
            __builtin_amdgcn_s_barrier();                                                \
            __builtin_amdgcn_sched_barrier(0);                                           \
            if (DOISS_) { ISSUE_B((nti_), (h_) ^ 1); }                                   \
            const char* Bs_ = Bst[h_];                                                   \
            __builtin_amdgcn_s_setprio(1);                                               \
            _Pragma("unroll")                                                            \
            for (int sub = 0; sub < 2; ++sub) {                                          \
                _Pragma("unroll")                                                        \
                for (int kk = 0; kk < 2; ++kk) {                                         \
                    const int cb = kk * 4 + quad;                                        \
                    _Pragma("unroll")                                                    \
                    for (int ni = 0; ni < 8; ++ni) {                                     \
                        half8 bh = ldsr(Bs_ + sub * 16384, ni * 16 + col, cb);           \
                        acc[0][ni] = __builtin_amdgcn_mfma_f32_16x16x32_f16(             \
                            Ah[0][(h_) * 4 + sub * 2 + kk], bh, acc[0][ni], 0, 0, 0);    \
                        acc[1][ni] = __builtin_amdgcn_mfma_f32_16x16x32_f16(             \
                            Ah[1][(h_) * 4 + sub * 2 + kk], bh, acc[1][ni], 0, 0, 0);    \
                    }                                                                    \
                }                                                                        \
            }                                                                            \
            __builtin_amdgcn_s_setprio(0);                                               \
        }

    ISSUE_B(0, 0);

    for (int nt = 0; nt < 8; ++nt) {
        const int n0 = nt * 128;
        floatx4 acc[2][8] = {};
        STAGE(0, 1, nt)                 // dims   0..127, prefetch (nt, h=1)
        STAGE(1, (nt < 7), nt + 1)      // dims 128..255, prefetch (nt+1, h=0)
        // ---- per-nt epilogue: plain f32 top-2 + argmin (ties -> refine) ----
        float ev[8];
        #pragma unroll
        for (int ni = 0; ni < 8; ++ni) ev[ni] = eef_lds[n0 + ni * 16 + col];
        #pragma unroll
        for (int mi = 0; mi < 2; ++mi) {
            #pragma unroll
            for (int reg = 0; reg < 4; ++reg) {
                float v1 = 1e30f, v2 = 1e30f; int i1 = 0;
                #pragma unroll
                for (int ni = 0; ni < 8; ++ni) {
                    float val = fmaf(-2.0f, acc[mi][ni][reg], ev[ni]);
                    int n = n0 + ni * 16 + col;
                    bool lt1 = val < v1;
                    bool lt2 = val < v2;
                    float nv2 = lt1 ? v1 : (lt2 ? val : v2);
                    v1 = lt1 ? val : v1;
                    i1 = lt1 ? n : i1;
                    v2 = nv2;
                }
                #pragma unroll
                for (int off = 1; off < 16; off <<= 1) {
                    float o1 = __shfl_xor(v1, off, 16);
                    float o2 = __shfl_xor(v2, off, 16);
                    int   oi = __shfl_xor(i1, off, 16);
                    bool sw = o1 < v1;
                    float hi = sw ? v1 : o1;          // max(v1, o1)
                    v1 = sw ? o1 : v1;
                    i1 = sw ? oi : i1;
                    v2 = fminf(fminf(v2, o2), hi);
                }
                if (col == 0) {                       // same lane owns this row every nt
                    int row = w * 32 + mi * 16 + quad * 4 + reg;
                    float t1 = tv1[row], t2 = tv2[row];
                    bool sw = v1 < t1;
                    float hi = sw ? t1 : v1;          // max(t1, v1)
                    tv2[row] = fminf(fminf(t2, v2), hi);
                    tv1[row] = sw ? v1 : t1;
                    if (sw) ti1[row] = i1;
                }
            }
        }
    }

    // ---- final: resolve idx / flag near-ties ----
    __syncthreads();
    if (t < 128) {
        float v1 = tv1[t], v2 = tv2[t];
        int rid = (b0 + t) * KC + k;
        if (v2 - v1 < TAU) {
            int pos = atomicAdd(flag_cnt, 1);
            flag_list[pos] = rid;
            idx_lds[t] = -1;
        } else {
            int n = ti1[t];
            idx_lds[t] = n;
            out_idx[rid] = (float)n;
        }
    }
    __syncthreads();

    // ---- fused gather (out_q) + exact fp64 loss for resolved rows ----
    double s = 0.0;
    #pragma unroll
    for (int rr = 0; rr < 8; ++rr) {
        int r = rr * 16 + (t >> 4);
        int c = t & 15;
        int n = idx_lds[r];
        if (n >= 0) {
            const float4* xp = (const float4*)(x + ((size_t)(b0 + r) * KC + k) * DC);
            const float4* ep = (const float4*)(entries + ((size_t)k * NC + n) * DC);
            float4* op = (float4*)(out_q + ((size_t)(b0 + r) * KC + k) * DC);
            #pragma unroll
            for (int j = 0; j < 4; ++j) {
                int ci = j * 16 + c;
                float4 xv = xp[ci], evv = ep[ci];
                op[ci] = evv;
                double d0 = (double)xv.x - evv.x, d1 = (double)xv.y - evv.y;
                double d2 = (double)xv.z - evv.z, d3 = (double)xv.w - evv.w;
                s += d0 * d0 + d1 * d1 + d2 * d2 + d3 * d3;
            }
        }
    }
    red[t] = s;
    __syncthreads();
    for (int off2 = 128; off2 > 0; off2 >>= 1) {
        if (t < off2) red[t] += red[t + off2];
        __syncthreads();
    }
    if (t == 0) partial[blockIdx.x] = red[0];
    #undef STAGE
    #undef ISSUE_B
}

// ---------------------------------------------------------------------------
// REF: exact fp64 re-resolution of flagged rows. COALESCED: block per row,
// wave per 256 entries; per entry ONE 1KB coalesced wave-load (lane l holds
// dims 4l..4l+3), fp64 partials, shfl_down double reduce. Replaces the
// thread-per-entry scan whose 64-way address divergence serialized the
// address unit (measured 131 us for ~960 rows).
// ---------------------------------------------------------------------------
__global__ __launch_bounds__(256) void refine_kernel(const float* __restrict__ x,
                                                     const float* __restrict__ entries,
                                                     const int* __restrict__ flag_list,
                                                     const int* __restrict__ flag_cnt,
                                                     float* __restrict__ out_idx,
                                                     float* __restrict__ out_q,
                                                     double* __restrict__ refAcc) {
    __shared__ double wbest[4];
    __shared__ int    wbn[4];
    __shared__ int    win;
    const int t = threadIdx.x, wave = t >> 6, lane = t & 63;
    const int cnt = *flag_cnt;
    for (int i = blockIdx.x; i < cnt; i += gridDim.x) {
        const int rid = flag_list[i];
        const int k = rid & 7;
        float4 xv = ((const float4*)(x + (size_t)rid * DC))[lane];
        const double xd0 = xv.x, xd1 = xv.y, xd2 = xv.z, xd3 = xv.w;
        // wave owns entries [wave*256, wave*256+256); lane l reads dims 4l..4l+3
        const float4* Ek = (const float4*)(entries + (size_t)k * NC * DC)
                         + (size_t)(wave * 256) * 64 + lane;
        double best = 1.0e300; int bn = 0;
        #pragma unroll 2
        for (int e = 0; e < 256; e += 2) {
            float4 ea = Ek[(size_t)e * 64];
            float4 eb = Ek[(size_t)(e + 1) * 64];
            double a0 = xd0 - ea.x, a1 = xd1 - ea.y, a2 = xd2 - ea.z, a3 = xd3 - ea.w;
            double b0 = xd0 - eb.x, b1 = xd1 - eb.y, b2 = xd2 - eb.z, b3 = xd3 - eb.w;
            double sa = (a0 * a0 + a1 * a1) + (a2 * a2 + a3 * a3);
            double sb = (b0 * b0 + b1 * b1) + (b2 * b2 + b3 * b3);
            #pragma unroll
            for (int off = 32; off > 0; off >>= 1) {
                sa += __shfl_down(sa, off, 64);
                sb += __shfl_down(sb, off, 64);
            }
            if (lane == 0) {      // ascending e + strict < => smallest-n tie-break
                if (sa < best) { best = sa; bn = wave * 256 + e; }
                if (sb < best) { best = sb; bn = wave * 256 + e + 1; }
            }
        }
        __syncthreads();          // wbest/wbn reuse across grid-stride iterations
        if (lane == 0) { wbest[wave] = best; wbn[wave] = bn; }
        __syncthreads();
        if (t == 0) {
            double b = wbest[0]; int n = wbn[0];
            for (int wv = 1; wv < 4; ++wv) {
                if (wbest[wv] < b || (wbest[wv] == b && wbn[wv] < n)) {
                    b = wbest[wv]; n = wbn[wv];
                }
            }
            out_idx[rid] = (float)n;
            win = n;
            atomicAdd(refAcc, b);
        }
        __syncthreads();
        out_q[(size_t)rid * DC + t] = entries[((size_t)k * NC + win) * DC + t];
    }
}

__global__ __launch_bounds__(256) void finalize_kernel(const double* __restrict__ partial,
                                                       const double* __restrict__ refAcc,
                                                       float* __restrict__ out) {
    __shared__ double red[256];
    const int t = threadIdx.x;
    double s = 0.0;
    for (int i = t; i < 512; i += 256) s += partial[i];
    red[t] = s;
    __syncthreads();
    for (int off = 128; off > 0; off >>= 1) {
        if (t < off) red[t] += red[t + off];
        __syncthreads();
    }
    if (t == 0) {
        double L = (red[0] + *refAcc) * (1.0 / 65536.0);
        out[(size_t)BATCH * KC * DC + BATCH * KC + 0] = (float)L;
        out[(size_t)BATCH * KC * DC + BATCH * KC + 1] = (float)(0.25 * L);
    }
}

extern "C" void kernel_launch(void* const* d_in, const int* in_sizes, int n_in,
                              void* d_out, int out_size, void* d_ws, size_t ws_size,
                              hipStream_t stream) {
    const float* x       = (const float*)d_in[0];   // [8192, 8, 256]
    const float* entries = (const float*)d_in[1];   // [8, 1024, 256]
    float* out = (float*)d_out;

    char* ws = (char*)d_ws;
    int*      flag_cnt  = (int*)ws;                         // +0
    double*   refAcc    = (double*)(ws + 8);                // +8
    double*   partial   = (double*)(ws + 4096);             // 512 doubles
    float*    eef       = (float*)(ws + 65536);             // 32 KB
    int*      flag_list = (int*)(ws + 131072);              // 256 KB
    _Float16* Ecat      = (_Float16*)(ws + 1048576);        // 4 MB

    float* out_q   = out;                                   // 16,777,216 floats
    float* out_idx = out + (size_t)BATCH * KC * DC;         // 65,536 floats

    hipMemsetAsync(ws, 0, 16, stream);
    prep_e_kernel<<<KC * NC / 4, 256, 0, stream>>>(entries, Ecat, eef);
    vq_gemm<<<512, 256, 0, stream>>>(x, entries, Ecat, eef, out_idx, out_q,
                                     partial, flag_list, flag_cnt);
    refine_kernel<<<512, 256, 0, stream>>>(x, entries, flag_list, flag_cnt,
                                           out_idx, out_q, refAcc);
    finalize_kernel<<<1, 256, 0, stream>>>(partial, refAcc, out);
}

// Round 7
// 254.057 us; speedup vs baseline: 1.3495x; 1.3495x over previous
//
#include <hip/hip_runtime.h>
#include <cstdint>
#include <cstddef>

#define BATCH 8192
#define KC 8
#define NC 1024
#define DC 256
// Single-pass f16 GEMM: measured flag-rate 1.5% at TAU=0.15, ~1.0% at 0.10
// (cnt~640, WRITE_SIZE-confirmed). TAU = 0.10 ~ 11 sigma of the distance
// noise; flagged rows re-resolved exactly in fp64 by refine_scan/pick.
#define TAU 0.10f

typedef __attribute__((ext_vector_type(8))) _Float16 half8;
typedef __attribute__((ext_vector_type(4))) _Float16 half4;
typedef __attribute__((ext_vector_type(4))) float floatx4;

__device__ __forceinline__ void async_load16(const void* g, void* l) {
    __builtin_amdgcn_global_load_lds((const __attribute__((address_space(1))) uint32_t*)g,
                                     (__attribute__((address_space(3))) uint32_t*)l, 16, 0, 0);
}

// XOR-swizzled 16KB LDS sub-tile (128 rows x 64 halfs): row r, 16B chunk c at slot c^(r&7)
__device__ __forceinline__ int lidx(int r, int c) {
    return (r >> 3) * 1024 + (r & 7) * 128 + ((c ^ (r & 7)) * 16);
}
__device__ __forceinline__ half8 ldsr(const char* base, int r, int c) {
    return *(const half8*)(base + lidx(r, c));
}

// ---------------------------------------------------------------------------
// P: entries -> Eh f16 [row][256]; eef = fp32(|e|^2 via fp64)
// ---------------------------------------------------------------------------
__global__ __launch_bounds__(256) void prep_e_kernel(const float* __restrict__ entries,
                                                     _Float16* __restrict__ Ecat,
                                                     float* __restrict__ eef) {
    int wave = threadIdx.x >> 6, lane = threadIdx.x & 63;
    int row = blockIdx.x * 4 + wave;            // [0, 8192) = k*NC + n
    float4 v = ((const float4*)(entries + (size_t)row * DC))[lane];
    half4 h;
    h.x = (_Float16)v.x; h.y = (_Float16)v.y; h.z = (_Float16)v.z; h.w = (_Float16)v.w;
    *(half4*)(Ecat + (size_t)row * 256 + lane * 4) = h;
    double s = (double)v.x * v.x + (double)v.y * v.y + (double)v.z * v.z + (double)v.w * v.w;
    #pragma unroll
    for (int off = 32; off > 0; off >>= 1) s += __shfl_down(s, off, 64);
    if (lane == 0) eef[row] = (float)s;
}

// ---------------------------------------------------------------------------
// GEMM: grid 512 (k = blk&7 -> XCD-pinned, bt = blk>>3). 4 waves x 32 rows.
// SINGLE-PASS f16 (xh*eh only); accuracy recovered by TAU flagging + fp64
// refine. A full-K in registers; B streamed via global_load_lds, 2-ring of
// 32KB stage buffers (128-dim slices = 2 swizzled 16KB subtiles).
// ---------------------------------------------------------------------------
__global__ __launch_bounds__(256, 2) void vq_gemm(const float* __restrict__ x,
                                                  const float* __restrict__ entries,
                                                  const _Float16* __restrict__ Ecat,
                                                  const float* __restrict__ eef,
                                                  float* __restrict__ out_idx,
                                                  float* __restrict__ out_q,
                                                  double* __restrict__ partial,
                                                  int* __restrict__ flag_list,
                                                  int* __restrict__ flag_cnt) {
    __shared__ alignas(16) char Bst[2][32768];   // buf = 2 x 16KB subtiles (64 dims each)
    __shared__ float eef_lds[NC];
    __shared__ float tv1[128];
    __shared__ float tv2[128];
    __shared__ int   ti1[128];
    __shared__ int   idx_lds[128];
    __shared__ double red[256];

    const int t = threadIdx.x;
    const int k  = blockIdx.x & 7;
    const int b0 = (blockIdx.x >> 3) * 128;
    const int w = t >> 6, lane = t & 63;
    const int quad = lane >> 4, col = lane & 15;
    const int rl = lane >> 3;
    const int cs = (lane & 7) ^ rl;

    { float4 v = ((const float4*)(eef + (size_t)k * NC))[t]; *(float4*)(eef_lds + t * 4) = v; }
    if (t < 128) { tv1[t] = 1e30f; tv2[t] = 1e30f; ti1[t] = 0; }

    // ---- A fragments: full K=256 in registers, plain f16 ----
    half8 Ah[2][8];
    #pragma unroll
    for (int mi = 0; mi < 2; ++mi) {
        const float* xrow = x + ((size_t)(b0 + w * 32 + mi * 16 + col) * KC + k) * DC + quad * 8;
        #pragma unroll
        for (int ks = 0; ks < 8; ++ks) {
            float4 u0 = *(const float4*)(xrow + ks * 32);
            float4 u1 = *(const float4*)(xrow + ks * 32 + 4);
            float f[8] = {u0.x, u0.y, u0.z, u0.w, u1.x, u1.y, u1.z, u1.w};
            half8 h;
            #pragma unroll
            for (int j = 0; j < 8; ++j) h[j] = (_Float16)f[j];
            Ah[mi][ks] = h;
        }
    }

    const char* EcatK = (const char*)(Ecat + (size_t)k * NC * 256);   // 512B per col

    #define ISSUE_B(nt_, h_)                                                             \
        {                                                                                \
            char* bb_ = Bst[h_];                                                         \
            _Pragma("unroll")                                                            \
            for (int j = 0; j < 8; ++j) {                                                \
                int li_ = w * 8 + j; int sub_ = li_ >> 4, grp_ = li_ & 15;               \
                const char* src_ = EcatK + (size_t)((nt_) * 128 + grp_ * 8 + rl) * 512   \
                                 + ((h_) * 128 + sub_ * 64) * 2 + cs * 16;               \
                async_load16(src_, bb_ + sub_ * 16384 + grp_ * 1024 + lane * 16);        \
            }                                                                            \
        }

    #define STAGE(h_, DOISS_, nti_)                                                      \
        {                                                                                \
            asm volatile("s_waitcnt vmcnt(0)" ::: "memory");                             \
            __builtin_amdgcn_s_barrier();                                                \
            __builtin_amdgcn_sched_barrier(0);                                           \
            if (DOISS_) { ISSUE_B((nti_), (h_) ^ 1); }                                   \
            const char* Bs_ = Bst[h_];                                                   \
            __builtin_amdgcn_s_setprio(1);                                               \
            _Pragma("unroll")                                                            \
            for (int sub = 0; sub < 2; ++sub) {                                          \
                _Pragma("unroll")                                                        \
                for (int kk = 0; kk < 2; ++kk) {                                         \
                    const int cb = kk * 4 + quad;                                        \
                    _Pragma("unroll")                                                    \
                    for (int ni = 0; ni < 8; ++ni) {                                     \
                        half8 bh = ldsr(Bs_ + sub * 16384, ni * 16 + col, cb);           \
                        acc[0][ni] = __builtin_amdgcn_mfma_f32_16x16x32_f16(             \
                            Ah[0][(h_) * 4 + sub * 2 + kk], bh, acc[0][ni], 0, 0, 0);    \
                        acc[1][ni] = __builtin_amdgcn_mfma_f32_16x16x32_f16(             \
                            Ah[1][(h_) * 4 + sub * 2 + kk], bh, acc[1][ni], 0, 0, 0);    \
                    }                                                                    \
                }                                                                        \
            }                                                                            \
            __builtin_amdgcn_s_setprio(0);                                               \
        }

    ISSUE_B(0, 0);

    for (int nt = 0; nt < 8; ++nt) {
        const int n0 = nt * 128;
        floatx4 acc[2][8] = {};
        STAGE(0, 1, nt)                 // dims   0..127, prefetch (nt, h=1)
        STAGE(1, (nt < 7), nt + 1)      // dims 128..255, prefetch (nt+1, h=0)
        // ---- per-nt epilogue: plain f32 top-2 + argmin (ties -> refine) ----
        float ev[8];
        #pragma unroll
        for (int ni = 0; ni < 8; ++ni) ev[ni] = eef_lds[n0 + ni * 16 + col];
        #pragma unroll
        for (int mi = 0; mi < 2; ++mi) {
            #pragma unroll
            for (int reg = 0; reg < 4; ++reg) {
                float v1 = 1e30f, v2 = 1e30f; int i1 = 0;
                #pragma unroll
                for (int ni = 0; ni < 8; ++ni) {
                    float val = fmaf(-2.0f, acc[mi][ni][reg], ev[ni]);
                    int n = n0 + ni * 16 + col;
                    bool lt1 = val < v1;
                    bool lt2 = val < v2;
                    float nv2 = lt1 ? v1 : (lt2 ? val : v2);
                    v1 = lt1 ? val : v1;
                    i1 = lt1 ? n : i1;
                    v2 = nv2;
                }
                #pragma unroll
                for (int off = 1; off < 16; off <<= 1) {
                    float o1 = __shfl_xor(v1, off, 16);
                    float o2 = __shfl_xor(v2, off, 16);
                    int   oi = __shfl_xor(i1, off, 16);
                    bool sw = o1 < v1;
                    float hi = sw ? v1 : o1;          // max(v1, o1)
                    v1 = sw ? o1 : v1;
                    i1 = sw ? oi : i1;
                    v2 = fminf(fminf(v2, o2), hi);
                }
                if (col == 0) {                       // same lane owns this row every nt
                    int row = w * 32 + mi * 16 + quad * 4 + reg;
                    float t1 = tv1[row], t2 = tv2[row];
                    bool sw = v1 < t1;
                    float hi = sw ? t1 : v1;          // max(t1, v1)
                    tv2[row] = fminf(fminf(t2, v2), hi);
                    tv1[row] = sw ? v1 : t1;
                    if (sw) ti1[row] = i1;
                }
            }
        }
    }

    // ---- final: resolve idx / flag near-ties ----
    __syncthreads();
    if (t < 128) {
        float v1 = tv1[t], v2 = tv2[t];
        int rid = (b0 + t) * KC + k;
        if (v2 - v1 < TAU) {
            int pos = atomicAdd(flag_cnt, 1);
            flag_list[pos] = rid;
            idx_lds[t] = -1;
        } else {
            int n = ti1[t];
            idx_lds[t] = n;
            out_idx[rid] = (float)n;
        }
    }
    __syncthreads();

    // ---- fused gather (out_q) + exact fp64 loss for resolved rows ----
    double s = 0.0;
    #pragma unroll
    for (int rr = 0; rr < 8; ++rr) {
        int r = rr * 16 + (t >> 4);
        int c = t & 15;
        int n = idx_lds[r];
        if (n >= 0) {
            const float4* xp = (const float4*)(x + ((size_t)(b0 + r) * KC + k) * DC);
            const float4* ep = (const float4*)(entries + ((size_t)k * NC + n) * DC);
            float4* op = (float4*)(out_q + ((size_t)(b0 + r) * KC + k) * DC);
            #pragma unroll
            for (int j = 0; j < 4; ++j) {
                int ci = j * 16 + c;
                float4 xv = xp[ci], evv = ep[ci];
                op[ci] = evv;
                double d0 = (double)xv.x - evv.x, d1 = (double)xv.y - evv.y;
                double d2 = (double)xv.z - evv.z, d3 = (double)xv.w - evv.w;
                s += d0 * d0 + d1 * d1 + d2 * d2 + d3 * d3;
            }
        }
    }
    red[t] = s;
    __syncthreads();
    for (int off2 = 128; off2 > 0; off2 >>= 1) {
        if (t < off2) red[t] += red[t + off2];
        __syncthreads();
    }
    if (t == 0) partial[blockIdx.x] = red[0];
    #undef STAGE
    #undef ISSUE_B
}

// ---------------------------------------------------------------------------
// REF-SCAN: work item = (flagged row, 128-entry segment); cnt*8 items over
// the grid. Stage the 128x64-dim entry slice in LDS (coalesced float4 reads,
// pad-67 stride -> 2 lanes/bank = conflict-free), 2 threads/entry fp64
// partials, shfl(1) + block tree, then atomicMin of a packed u64 key
// (double bits & ~1023 | n : monotonic for positive doubles, smallest-n
// tie-break) into slots[row]. Replaces the serial wave-per-entry reduce
// (165 us: dependent load->12-shfl chain, ~1.3 rows/block parallelism).
// ---------------------------------------------------------------------------
__global__ __launch_bounds__(256) void refine_scan(const float* __restrict__ x,
                                                   const float* __restrict__ entries,
                                                   const int* __restrict__ flag_list,
                                                   const int* __restrict__ flag_cnt,
                                                   unsigned long long* __restrict__ slots) {
    __shared__ float xs[DC];
    __shared__ float tile[128 * 67];
    __shared__ double bd[256];
    __shared__ int    bi[256];
    const int t = threadIdx.x;
    const int cnt = *flag_cnt;
    const int e = t >> 1, dh = (t & 1) * 32;
    for (int wi = blockIdx.x; wi < cnt * 8; wi += gridDim.x) {
        const int i = wi >> 3, seg = wi & 7;
        const int rid = flag_list[i];
        const int k = rid & 7;
        const int nb = seg * 128;
        __syncthreads();                       // xs/tile/bd reuse across items
        xs[t] = x[(size_t)rid * DC + t];
        double acc = 0.0;
        #pragma unroll
        for (int c = 0; c < 4; ++c) {
            __syncthreads();                   // xs ready / prev compute done
            #pragma unroll
            for (int it = 0; it < 8; ++it) {   // stage 128 rows x 64 dims
                int r = it * 16 + (t >> 4), c16 = t & 15;
                float4 v = *(const float4*)(entries
                    + ((size_t)k * NC + nb + r) * DC + c * 64 + c16 * 4);
                float* dst = &tile[r * 67 + c16 * 4];
                dst[0] = v.x; dst[1] = v.y; dst[2] = v.z; dst[3] = v.w;
            }
            __syncthreads();
            const float* xp = xs + c * 64 + dh;
            const float* ep = &tile[e * 67 + dh];
            #pragma unroll
            for (int d = 0; d < 32; ++d) {
                double df = (double)xp[d] - (double)ep[d];
                acc += df * df;
            }
        }
        acc += __shfl_xor(acc, 1, 64);         // pair-combine: full 256-dim dist
        bd[t] = acc; bi[t] = nb + e;           // pairs duplicated - harmless
        __syncthreads();
        for (int s2 = 128; s2 > 0; s2 >>= 1) {
            if (t < s2) {
                if (bd[t + s2] < bd[t] || (bd[t + s2] == bd[t] && bi[t + s2] < bi[t])) {
                    bd[t] = bd[t + s2]; bi[t] = bi[t + s2];
                }
            }
            __syncthreads();
        }
        if (t == 0) {
            unsigned long long key =
                ((unsigned long long)__double_as_longlong(bd[0]) & ~1023ull)
                | (unsigned long long)(unsigned)bi[0];
            atomicMin(&slots[i], key);
        }
    }
}

// ---------------------------------------------------------------------------
// REF-PICK: row-per-block; decode winning (dist, n) from slot, write idx,
// coalesced out_q gather, loss atomicAdd.
// ---------------------------------------------------------------------------
__global__ __launch_bounds__(256) void refine_pick(const float* __restrict__ entries,
                                                   const int* __restrict__ flag_list,
                                                   const int* __restrict__ flag_cnt,
                                                   const unsigned long long* __restrict__ slots,
                                                   float* __restrict__ out_idx,
                                                   float* __restrict__ out_q,
                                                   double* __restrict__ refAcc) {
    const int t = threadIdx.x;
    const int cnt = *flag_cnt;
    for (int i = blockIdx.x; i < cnt; i += gridDim.x) {
        unsigned long long key = slots[i];
        int n = (int)(key & 1023ull);
        int rid = flag_list[i];
        int k = rid & 7;
        out_q[(size_t)rid * DC + t] = entries[((size_t)k * NC + n) * DC + t];
        if (t == 0) {
            out_idx[rid] = (float)n;
            atomicAdd(refAcc, __longlong_as_double((long long)(key & ~1023ull)));
        }
    }
}

__global__ __launch_bounds__(256) void finalize_kernel(const double* __restrict__ partial,
                                                       const double* __restrict__ refAcc,
                                                       float* __restrict__ out) {
    __shared__ double red[256];
    const int t = threadIdx.x;
    double s = 0.0;
    for (int i = t; i < 512; i += 256) s += partial[i];
    red[t] = s;
    __syncthreads();
    for (int off = 128; off > 0; off >>= 1) {
        if (t < off) red[t] += red[t + off];
        __syncthreads();
    }
    if (t == 0) {
        double L = (red[0] + *refAcc) * (1.0 / 65536.0);
        out[(size_t)BATCH * KC * DC + BATCH * KC + 0] = (float)L;
        out[(size_t)BATCH * KC * DC + BATCH * KC + 1] = (float)(0.25 * L);
    }
}

extern "C" void kernel_launch(void* const* d_in, const int* in_sizes, int n_in,
                              void* d_out, int out_size, void* d_ws, size_t ws_size,
                              hipStream_t stream) {
    const float* x       = (const float*)d_in[0];   // [8192, 8, 256]
    const float* entries = (const float*)d_in[1];   // [8, 1024, 256]
    float* out = (float*)d_out;

    char* ws = (char*)d_ws;
    int*      flag_cnt  = (int*)ws;                         // +0
    double*   refAcc    = (double*)(ws + 8);                // +8
    double*   partial   = (double*)(ws + 4096);             // 512 doubles
    float*    eef       = (float*)(ws + 65536);             // 32 KB
    int*      flag_list = (int*)(ws + 131072);              // 256 KB
    _Float16* Ecat      = (_Float16*)(ws + 1048576);        // 4 MB
    unsigned long long* slots = (unsigned long long*)(ws + 5242880);  // 512 KB

    float* out_q   = out;                                   // 16,777,216 floats
    float* out_idx = out + (size_t)BATCH * KC * DC;         // 65,536 floats

    hipMemsetAsync(ws, 0, 16, stream);
    hipMemsetAsync(slots, 0xFF, (size_t)65536 * 8, stream); // u64 max
    prep_e_kernel<<<KC * NC / 4, 256, 0, stream>>>(entries, Ecat, eef);
    vq_gemm<<<512, 256, 0, stream>>>(x, entries, Ecat, eef, out_idx, out_q,
                                     partial, flag_list, flag_cnt);
    refine_scan<<<4096, 256, 0, stream>>>(x, entries, flag_list, flag_cnt, slots);
    refine_pick<<<512, 256, 0, stream>>>(entries, flag_list, flag_cnt, slots,
                                         out_idx, out_q, refAcc);
    finalize_kernel<<<1, 256, 0, stream>>>(partial, refAcc, out);
}

// Round 8
// 225.862 us; speedup vs baseline: 1.5180x; 1.1248x over previous
//
#include <hip/hip_runtime.h>
#include <cstdint>
#include <cstddef>

#define BATCH 8192
#define KC 8
#define NC 1024
#define DC 256
// Single-pass f16 GEMM: measured flag-rate ~1.0% at TAU=0.10 (cnt~640,
// WRITE_SIZE-confirmed). Flagged rows re-resolved exactly in fp64.
#define TAU 0.10f

typedef __attribute__((ext_vector_type(8))) _Float16 half8;
typedef __attribute__((ext_vector_type(4))) _Float16 half4;
typedef __attribute__((ext_vector_type(4))) float floatx4;

__device__ __forceinline__ void async_load16(const void* g, void* l) {
    __builtin_amdgcn_global_load_lds((const __attribute__((address_space(1))) uint32_t*)g,
                                     (__attribute__((address_space(3))) uint32_t*)l, 16, 0, 0);
}

// XOR-swizzled 16KB LDS sub-tile (128 rows x 64 halfs): row r, 16B chunk c at slot c^(r&7)
__device__ __forceinline__ int lidx(int r, int c) {
    return (r >> 3) * 1024 + (r & 7) * 128 + ((c ^ (r & 7)) * 16);
}
__device__ __forceinline__ half8 ldsr(const char* base, int r, int c) {
    return *(const half8*)(base + lidx(r, c));
}

// ---------------------------------------------------------------------------
// P: entries -> Eh f16 [row][256]; eef = fp32(|e|^2 via fp64)
// ---------------------------------------------------------------------------
__global__ __launch_bounds__(256) void prep_e_kernel(const float* __restrict__ entries,
                                                     _Float16* __restrict__ Ecat,
                                                     float* __restrict__ eef) {
    int wave = threadIdx.x >> 6, lane = threadIdx.x & 63;
    int row = blockIdx.x * 4 + wave;            // [0, 8192) = k*NC + n
    float4 v = ((const float4*)(entries + (size_t)row * DC))[lane];
    half4 h;
    h.x = (_Float16)v.x; h.y = (_Float16)v.y; h.z = (_Float16)v.z; h.w = (_Float16)v.w;
    *(half4*)(Ecat + (size_t)row * 256 + lane * 4) = h;
    double s = (double)v.x * v.x + (double)v.y * v.y + (double)v.z * v.z + (double)v.w * v.w;
    #pragma unroll
    for (int off = 32; off > 0; off >>= 1) s += __shfl_down(s, off, 64);
    if (lane == 0) eef[row] = (float)s;
}

// ---------------------------------------------------------------------------
// GEMM: grid 512 (k = blk&7 -> XCD-pinned, bt = blk>>3). 4 waves x 32 rows.
// SINGLE-PASS f16; TAU flagging + fp64 refine recovers accuracy.
// Epilogue: LANE-LOCAL top-2 across all nt (24 VGPR), ONE 16-lane butterfly
// at the end -- removes the per-nt shuffle trees (768 -> 96 DS ops/thread)
// that competed with staging ds_reads.
// ---------------------------------------------------------------------------
__global__ __launch_bounds__(256, 2) void vq_gemm(const float* __restrict__ x,
                                                  const float* __restrict__ entries,
                                                  const _Float16* __restrict__ Ecat,
                                                  const float* __restrict__ eef,
                                                  float* __restrict__ out_idx,
                                                  float* __restrict__ out_q,
                                                  double* __restrict__ partial,
                                                  int* __restrict__ flag_list,
                                                  int* __restrict__ flag_cnt) {
    __shared__ alignas(16) char Bst[2][32768];   // buf = 2 x 16KB subtiles (64 dims each)
    __shared__ float eef_lds[NC];
    __shared__ float tv1[128];
    __shared__ float tv2[128];
    __shared__ int   ti1[128];
    __shared__ int   idx_lds[128];
    __shared__ double red[256];

    const int t = threadIdx.x;
    const int k  = blockIdx.x & 7;
    const int b0 = (blockIdx.x >> 3) * 128;
    const int w = t >> 6, lane = t & 63;
    const int quad = lane >> 4, col = lane & 15;
    const int rl = lane >> 3;
    const int cs = (lane & 7) ^ rl;

    { float4 v = ((const float4*)(eef + (size_t)k * NC))[t]; *(float4*)(eef_lds + t * 4) = v; }

    // ---- A fragments: full K=256 in registers, plain f16 ----
    half8 Ah[2][8];
    #pragma unroll
    for (int mi = 0; mi < 2; ++mi) {
        const float* xrow = x + ((size_t)(b0 + w * 32 + mi * 16 + col) * KC + k) * DC + quad * 8;
        #pragma unroll
        for (int ks = 0; ks < 8; ++ks) {
            float4 u0 = *(const float4*)(xrow + ks * 32);
            float4 u1 = *(const float4*)(xrow + ks * 32 + 4);
            float f[8] = {u0.x, u0.y, u0.z, u0.w, u1.x, u1.y, u1.z, u1.w};
            half8 h;
            #pragma unroll
            for (int j = 0; j < 8; ++j) h[j] = (_Float16)f[j];
            Ah[mi][ks] = h;
        }
    }

    const char* EcatK = (const char*)(Ecat + (size_t)k * NC * 256);   // 512B per col

    #define ISSUE_B(nt_, h_)                                                             \
        {                                                                                \
            char* bb_ = Bst[h_];                                                         \
            _Pragma("unroll")                                                            \
            for (int j = 0; j < 8; ++j) {                                                \
                int li_ = w * 8 + j; int sub_ = li_ >> 4, grp_ = li_ & 15;               \
                const char* src_ = EcatK + (size_t)((nt_) * 128 + grp_ * 8 + rl) * 512   \
                                 + ((h_) * 128 + sub_ * 64) * 2 + cs * 16;               \
                async_load16(src_, bb_ + sub_ * 16384 + grp_ * 1024 + lane * 16);        \
            }                                                                            \
        }

    #define STAGE(h_, DOISS_, nti_)                                                      \
        {                                                                                \
            asm volatile("s_waitcnt vmcnt(0)" ::: "memory");                             \
            __builtin_amdgcn_s_barrier();                                                \
            __builtin_amdgcn_sched_barrier(0);                                           \
            if (DOISS_) { ISSUE_B((nti_), (h_) ^ 1); }                                   \
            const char* Bs_ = Bst[h_];                                                   \
            __builtin_amdgcn_s_setprio(1);                                               \
            _Pragma("unroll")                                                            \
            for (int sub = 0; sub < 2; ++sub) {                                          \
                _Pragma("unroll")                                                        \
                for (int kk = 0; kk < 2; ++kk) {                                         \
                    const int cb = kk * 4 + quad;                                        \
                    _Pragma("unroll")                                                    \
                    for (int ni = 0; ni < 8; ++ni) {                                     \
                        half8 bh = ldsr(Bs_ + sub * 16384, ni * 16 + col, cb);           \
                        acc[0][ni] = __builtin_amdgcn_mfma_f32_16x16x32_f16(             \
                            Ah[0][(h_) * 4 + sub * 2 + kk], bh, acc[0][ni], 0, 0, 0);    \
                        acc[1][ni] = __builtin_amdgcn_mfma_f32_16x16x32_f16(             \
                            Ah[1][(h_) * 4 + sub * 2 + kk], bh, acc[1][ni], 0, 0, 0);    \
                    }                                                                    \
                }                                                                        \
            }                                                                            \
            __builtin_amdgcn_s_setprio(0);                                               \
        }

    // ---- lane-local running top-2 per (mi,reg) across ALL nt ----
    float lv1[8], lv2[8]; int li1[8];
    #pragma unroll
    for (int q = 0; q < 8; ++q) { lv1[q] = 1e30f; lv2[q] = 1e30f; li1[q] = 0; }

    ISSUE_B(0, 0);

    for (int nt = 0; nt < 8; ++nt) {
        const int n0 = nt * 128;
        floatx4 acc[2][8] = {};
        STAGE(0, 1, nt)                 // dims   0..127, prefetch (nt, h=1)
        STAGE(1, (nt < 7), nt + 1)      // dims 128..255, prefetch (nt+1, h=0)
        // ---- per-nt epilogue: lane-local top-2 update only (no shuffles) ----
        float ev[8];
        #pragma unroll
        for (int ni = 0; ni < 8; ++ni) ev[ni] = eef_lds[n0 + ni * 16 + col];
        #pragma unroll
        for (int mi = 0; mi < 2; ++mi) {
            #pragma unroll
            for (int reg = 0; reg < 4; ++reg) {
                const int q = mi * 4 + reg;
                #pragma unroll
                for (int ni = 0; ni < 8; ++ni) {
                    float val = fmaf(-2.0f, acc[mi][ni][reg], ev[ni]);
                    int n = n0 + ni * 16 + col;
                    bool lt1 = val < lv1[q];
                    bool lt2 = val < lv2[q];
                    float nv2 = lt1 ? lv1[q] : (lt2 ? val : lv2[q]);
                    li1[q] = lt1 ? n : li1[q];
                    lv1[q] = lt1 ? val : lv1[q];
                    lv2[q] = nv2;
                }
            }
        }
    }

    // ---- ONE cross-lane top-2 reduce per (mi,reg); write-once to LDS ----
    #pragma unroll
    for (int mi = 0; mi < 2; ++mi) {
        #pragma unroll
        for (int reg = 0; reg < 4; ++reg) {
            const int q = mi * 4 + reg;
            float v1 = lv1[q], v2 = lv2[q]; int i1 = li1[q];
            #pragma unroll
            for (int off = 1; off < 16; off <<= 1) {
                float o1 = __shfl_xor(v1, off, 16);
                float o2 = __shfl_xor(v2, off, 16);
                int   oi = __shfl_xor(i1, off, 16);
                bool sw = o1 < v1;
                float hi = sw ? v1 : o1;          // max(v1, o1)
                v1 = sw ? o1 : v1;
                i1 = sw ? oi : i1;
                v2 = fminf(fminf(v2, o2), hi);
            }
            if (col == 0) {
                int row = w * 32 + mi * 16 + quad * 4 + reg;
                tv1[row] = v1; tv2[row] = v2; ti1[row] = i1;
            }
        }
    }

    // ---- final: resolve idx / flag near-ties (per-k flag lists) ----
    __syncthreads();
    if (t < 128) {
        float v1 = tv1[t], v2 = tv2[t];
        int rid = (b0 + t) * KC + k;
        if (v2 - v1 < TAU) {
            int pos = atomicAdd(&flag_cnt[k], 1);
            flag_list[k * 8192 + pos] = rid;
            idx_lds[t] = -1;
        } else {
            int n = ti1[t];
            idx_lds[t] = n;
            out_idx[rid] = (float)n;
        }
    }
    __syncthreads();

    // ---- fused gather (out_q) + exact fp64 loss for resolved rows ----
    double s = 0.0;
    #pragma unroll
    for (int rr = 0; rr < 8; ++rr) {
        int r = rr * 16 + (t >> 4);
        int c = t & 15;
        int n = idx_lds[r];
        if (n >= 0) {
            const float4* xp = (const float4*)(x + ((size_t)(b0 + r) * KC + k) * DC);
            const float4* ep = (const float4*)(entries + ((size_t)k * NC + n) * DC);
            float4* op = (float4*)(out_q + ((size_t)(b0 + r) * KC + k) * DC);
            #pragma unroll
            for (int j = 0; j < 4; ++j) {
                int ci = j * 16 + c;
                float4 xv = xp[ci], evv = ep[ci];
                op[ci] = evv;
                double d0 = (double)xv.x - evv.x, d1 = (double)xv.y - evv.y;
                double d2 = (double)xv.z - evv.z, d3 = (double)xv.w - evv.w;
                s += d0 * d0 + d1 * d1 + d2 * d2 + d3 * d3;
            }
        }
    }
    red[t] = s;
    __syncthreads();
    for (int off2 = 128; off2 > 0; off2 >>= 1) {
        if (t < off2) red[t] += red[t + off2];
        __syncthreads();
    }
    if (t == 0) partial[blockIdx.x] = red[0];
    #undef STAGE
    #undef ISSUE_B
}

// ---------------------------------------------------------------------------
// REF-SCAN (k-grouped): item = (k, 16-row group, 128-entry segment).
// Stage segment entries ONCE (XOR-swizzled LDS, 2-way-max conflicts) and the
// 16 x-rows; thread (r, eg) computes fp64 distances of row r vs entries
// eg*8..+8. 16x less entry traffic than row-per-item (640 MB -> 40 MB).
// Winner per (row,seg) via packed-u64 atomicMin into slots[k*8192+pos]
// (double bits & ~1023 | n : monotonic, smallest-n tie-break).
// ---------------------------------------------------------------------------
__global__ __launch_bounds__(256) void refine_scan(const float* __restrict__ x,
                                                   const float* __restrict__ entries,
                                                   const int* __restrict__ flag_list,
                                                   const int* __restrict__ flag_cnt,
                                                   unsigned long long* __restrict__ slots) {
    __shared__ alignas(16) char tileb[128 * 256];   // 128 entries x 64 dims (swizzled)
    __shared__ float xs[16 * 260];                  // 16 rows x 256 dims (pad 260)
    const int t = threadIdx.x;
    const int r = t >> 4, eg = t & 15;
    // item: it&7 = k, (it>>3)&7 = seg, it>>6 = g
    for (int it = blockIdx.x; it < 8 * 8 * 512; it += gridDim.x) {
        const int k = it & 7, seg = (it >> 3) & 7, g = it >> 6;
        const int cnt_k = flag_cnt[k];
        if (g * 16 >= cnt_k) continue;
        const int nrows = min(16, cnt_k - g * 16);
        const int myrow = (r < nrows) ? r : 0;
        const int rid = flag_list[k * 8192 + g * 16 + myrow];
        // stage xs: thread (rr = t>>4, c16 = t&15) loads 4 float4 of its row
        {
            const int rr = t >> 4, c16 = t & 15;
            const int rid2 = flag_list[k * 8192 + g * 16 + ((rr < nrows) ? rr : 0)];
            const float4* xp = (const float4*)(x + (size_t)rid2 * DC);
            #pragma unroll
            for (int j = 0; j < 4; ++j) {
                float4 v = xp[c16 * 4 + j];
                *(float4*)(xs + rr * 260 + (c16 * 4 + j) * 4) = v;
            }
        }
        double acc[8] = {};
        #pragma unroll
        for (int c = 0; c < 4; ++c) {
            // stage tile chunk c: 128 entries x 64 dims
            {
                const int c16 = t & 15;
                #pragma unroll
                for (int it2 = 0; it2 < 8; ++it2) {
                    int row = it2 * 16 + (t >> 4);
                    float4 v = *(const float4*)(entries
                        + ((size_t)k * NC + seg * 128 + row) * DC + c * 64 + c16 * 4);
                    *(float4*)(tileb + row * 256 + ((c16 ^ (row >> 3)) * 16)) = v;
                }
            }
            __syncthreads();
            const float* xpp = xs + r * 260 + c * 64;
            #pragma unroll 4
            for (int dq = 0; dq < 16; ++dq) {
                float4 xv = *(const float4*)(xpp + dq * 4);
                #pragma unroll
                for (int j = 0; j < 8; ++j) {
                    int e = eg * 8 + j;
                    float4 evv = *(const float4*)(tileb + e * 256 + ((dq ^ eg) * 16));
                    double d0 = (double)xv.x - (double)evv.x;
                    double d1 = (double)xv.y - (double)evv.y;
                    double d2 = (double)xv.z - (double)evv.z;
                    double d3 = (double)xv.w - (double)evv.w;
                    acc[j] += d0 * d0 + d1 * d1 + d2 * d2 + d3 * d3;
                }
            }
            __syncthreads();            // compute done before next chunk overwrites
        }
        // thread-local min over 8 entries (ascending j, strict < => smallest n)
        double best = acc[0]; int bn = seg * 128 + eg * 8;
        #pragma unroll
        for (int j = 1; j < 8; ++j) {
            if (acc[j] < best) { best = acc[j]; bn = seg * 128 + eg * 8 + j; }
        }
        unsigned long long key =
            ((unsigned long long)__double_as_longlong(best) & ~1023ull)
            | (unsigned long long)(unsigned)bn;
        // reduce across the 16 lanes sharing row r (contiguous lanes)
        #pragma unroll
        for (int off = 1; off < 16; off <<= 1) {
            unsigned long long o = __shfl_xor(key, off, 16);
            key = o < key ? o : key;
        }
        if (eg == 0 && r < nrows) {
            atomicMin(&slots[k * 8192 + g * 16 + r], key);
        }
        (void)rid;
    }
}

// ---------------------------------------------------------------------------
// REF-PICK: decode winner from slot, write idx, coalesced out_q, loss add.
// ---------------------------------------------------------------------------
__global__ __launch_bounds__(256) void refine_pick(const float* __restrict__ entries,
                                                   const int* __restrict__ flag_list,
                                                   const int* __restrict__ flag_cnt,
                                                   const unsigned long long* __restrict__ slots,
                                                   float* __restrict__ out_idx,
                                                   float* __restrict__ out_q,
                                                   double* __restrict__ refAcc) {
    const int t = threadIdx.x;
    for (int idx = blockIdx.x; idx < 8 * 8192; idx += gridDim.x) {
        const int k = idx >> 13, pos = idx & 8191;
        if (pos >= flag_cnt[k]) continue;
        unsigned long long key = slots[idx];
        int n = (int)(key & 1023ull);
        int rid = flag_list[idx];
        out_q[(size_t)rid * DC + t] = entries[((size_t)k * NC + n) * DC + t];
        if (t == 0) {
            out_idx[rid] = (float)n;
            atomicAdd(refAcc, __longlong_as_double((long long)(key & ~1023ull)));
        }
    }
}

__global__ __launch_bounds__(256) void finalize_kernel(const double* __restrict__ partial,
                                                       const double* __restrict__ refAcc,
                                                       float* __restrict__ out) {
    __shared__ double red[256];
    const int t = threadIdx.x;
    double s = 0.0;
    for (int i = t; i < 512; i += 256) s += partial[i];
    red[t] = s;
    __syncthreads();
    for (int off = 128; off > 0; off >>= 1) {
        if (t < off) red[t] += red[t + off];
        __syncthreads();
    }
    if (t == 0) {
        double L = (red[0] + *refAcc) * (1.0 / 65536.0);
        out[(size_t)BATCH * KC * DC + BATCH * KC + 0] = (float)L;
        out[(size_t)BATCH * KC * DC + BATCH * KC + 1] = (float)(0.25 * L);
    }
}

extern "C" void kernel_launch(void* const* d_in, const int* in_sizes, int n_in,
                              void* d_out, int out_size, void* d_ws, size_t ws_size,
                              hipStream_t stream) {
    const float* x       = (const float*)d_in[0];   // [8192, 8, 256]
    const float* entries = (const float*)d_in[1];   // [8, 1024, 256]
    float* out = (float*)d_out;

    char* ws = (char*)d_ws;
    int*      flag_cnt  = (int*)ws;                         // +0: int[8]
    double*   refAcc    = (double*)(ws + 64);               // +64
    double*   partial   = (double*)(ws + 4096);             // 512 doubles
    float*    eef       = (float*)(ws + 65536);             // 32 KB
    int*      flag_list = (int*)(ws + 131072);              // 8 lists x 8192
    _Float16* Ecat      = (_Float16*)(ws + 1048576);        // 4 MB
    unsigned long long* slots = (unsigned long long*)(ws + 5242880);  // 512 KB

    float* out_q   = out;                                   // 16,777,216 floats
    float* out_idx = out + (size_t)BATCH * KC * DC;         // 65,536 floats

    hipMemsetAsync(ws, 0, 128, stream);                     // flag_cnt[8] + refAcc
    hipMemsetAsync(slots, 0xFF, (size_t)65536 * 8, stream); // u64 max
    prep_e_kernel<<<KC * NC / 4, 256, 0, stream>>>(entries, Ecat, eef);
    vq_gemm<<<512, 256, 0, stream>>>(x, entries, Ecat, eef, out_idx, out_q,
                                     partial, flag_list, flag_cnt);
    refine_scan<<<512, 256, 0, stream>>>(x, entries, flag_list, flag_cnt, slots);
    refine_pick<<<512, 256, 0, stream>>>(entries, flag_list, flag_cnt, slots,
                                         out_idx, out_q, refAcc);
    finalize_kernel<<<1, 256, 0, stream>>>(partial, refAcc, out);
}